// Round 1
// baseline (2945.544 us; speedup 1.0000x reference)
//
#include <hip/hip_runtime.h>
#include <hip/hip_bf16.h>

#define NN 20000
#define EE 640000

__device__ __forceinline__ float sigf(float x) {
    // sigmoid via hw exp2 + rcp; saturates correctly (exp2(+inf)->inf, rcp(inf)->0)
    return __builtin_amdgcn_rcpf(1.0f + __builtin_amdgcn_exp2f(x * -1.442695041f));
}

__global__ void fill_zero_i32(int* __restrict__ p, int n) {
    int i = blockIdx.x * 256 + threadIdx.x;
    if (i < n) p[i] = 0;
}

__global__ void count_rows(const int* __restrict__ rows, int* __restrict__ cnt, int e) {
    int i = blockIdx.x * 256 + threadIdx.x;
    if (i < e) atomicAdd(&cnt[rows[i]], 1);
}

__global__ __launch_bounds__(1024) void scan_counts(const int* __restrict__ cnt,
                                                    int* __restrict__ off,
                                                    int* __restrict__ cursor, int n) {
    __shared__ int part[1024];
    int tid = threadIdx.x;
    const int per = (n + 1023) / 1024;
    int base = tid * per;
    int s = 0;
    for (int i = 0; i < per; ++i) {
        int idx = base + i;
        if (idx < n) s += cnt[idx];
    }
    part[tid] = s;
    __syncthreads();
    for (int d = 1; d < 1024; d <<= 1) {
        int v = (tid >= d) ? part[tid - d] : 0;
        __syncthreads();
        part[tid] += v;
        __syncthreads();
    }
    int run = (tid == 0) ? 0 : part[tid - 1];
    for (int i = 0; i < per; ++i) {
        int idx = base + i;
        if (idx < n) {
            off[idx] = run;
            cursor[idx] = run;
            run += cnt[idx];
        }
    }
    if (tid == 1023) off[n] = part[1023];
}

__global__ void scatter_edges(const int* __restrict__ rows, const int* __restrict__ cols,
                              const float* __restrict__ vals, int* __restrict__ cursor,
                              int* __restrict__ col_s, float* __restrict__ val_s, int e) {
    int i = blockIdx.x * 256 + threadIdx.x;
    if (i < e) {
        int p = atomicAdd(&cursor[rows[i]], 1);
        col_s[p] = cols[i];
        val_s[p] = vals[i];
    }
}

// C[M,Nc] = A[M,K] @ B[K,Nc]; 64x64 tile, 256 threads, 4x4 per thread.
// K % 16 == 0, Nc % 64 == 0; M guarded.
__global__ __launch_bounds__(256) void sgemm64(const float* __restrict__ A,
                                               const float* __restrict__ B,
                                               float* __restrict__ C, int M, int K, int Nc) {
    __shared__ float As[16][65];
    __shared__ float Bs[16][65];
    int tid = threadIdx.x;
    int tm = (tid >> 4) << 2;
    int tn = (tid & 15) << 2;
    int m0 = blockIdx.y * 64;
    int n0 = blockIdx.x * 64;
    float acc[4][4] = {};
    for (int k0 = 0; k0 < K; k0 += 16) {
        for (int i = tid; i < 64 * 16; i += 256) {
            int r = i >> 4, c = i & 15;
            int gr = m0 + r;
            As[c][r] = (gr < M) ? A[(long)gr * K + k0 + c] : 0.0f;
        }
        for (int i = tid; i < 16 * 64; i += 256) {
            int kk = i >> 6, c = i & 63;
            Bs[kk][c] = B[(long)(k0 + kk) * Nc + n0 + c];
        }
        __syncthreads();
        #pragma unroll
        for (int kk = 0; kk < 16; ++kk) {
            float a[4], b[4];
            #pragma unroll
            for (int x = 0; x < 4; ++x) a[x] = As[kk][tm + x];
            #pragma unroll
            for (int y = 0; y < 4; ++y) b[y] = Bs[kk][tn + y];
            #pragma unroll
            for (int x = 0; x < 4; ++x)
                #pragma unroll
                for (int y = 0; y < 4; ++y)
                    acc[x][y] = fmaf(a[x], b[y], acc[x][y]);
        }
        __syncthreads();
    }
    for (int x = 0; x < 4; ++x) {
        int gr = m0 + tm + x;
        if (gr < M) {
            #pragma unroll
            for (int y = 0; y < 4; ++y) C[(long)gr * Nc + n0 + tn + y] = acc[x][y];
        }
    }
}

// Y[row,:] = sum_e val[e] * X[col[e],:], D=64, one wave per row, lane = feature.
__global__ __launch_bounds__(256) void spmm_csr64(const int* __restrict__ off,
                                                  const int* __restrict__ col_s,
                                                  const float* __restrict__ val_s,
                                                  const float* __restrict__ X,
                                                  float* __restrict__ Y, int n) {
    int row = blockIdx.x * 4 + (threadIdx.x >> 6);
    if (row >= n) return;
    int lane = threadIdx.x & 63;
    int e0 = off[row], e1 = off[row + 1];
    float acc = 0.0f;
    for (int e = e0; e < e1; ++e) {
        acc = fmaf(val_s[e], X[(long)col_s[e] * 64 + lane], acc);
    }
    Y[(long)row * 64 + lane] = acc;
}

// A[i,j] = sigmoid(dot(Z[i], Z[j])), Z: [n,64]. 128x128 tile, 8x8 per thread.
__global__ __launch_bounds__(256) void decoder_zzT(const float* __restrict__ Z,
                                                   float* __restrict__ A, int n) {
    __shared__ float Zik[64][128];  // [k][m] transposed for contiguous m-reads
    __shared__ float Zjk[64][128];
    int tid = threadIdx.x;
    int i0 = blockIdx.y << 7;
    int j0 = blockIdx.x << 7;
    for (int t = tid; t < 128 * 16; t += 256) {
        int r = t >> 4, c4 = t & 15;
        int k = c4 << 2;
        float4 vi = make_float4(0.f, 0.f, 0.f, 0.f);
        float4 vj = make_float4(0.f, 0.f, 0.f, 0.f);
        if (i0 + r < n) vi = *(const float4*)(Z + (long)(i0 + r) * 64 + k);
        if (j0 + r < n) vj = *(const float4*)(Z + (long)(j0 + r) * 64 + k);
        Zik[k + 0][r] = vi.x; Zik[k + 1][r] = vi.y; Zik[k + 2][r] = vi.z; Zik[k + 3][r] = vi.w;
        Zjk[k + 0][r] = vj.x; Zjk[k + 1][r] = vj.y; Zjk[k + 2][r] = vj.z; Zjk[k + 3][r] = vj.w;
    }
    __syncthreads();
    int tm = (tid >> 4) << 3;
    int tn = (tid & 15) << 3;
    float acc[8][8] = {};
    #pragma unroll 4
    for (int k = 0; k < 64; ++k) {
        float a[8], b[8];
        #pragma unroll
        for (int x = 0; x < 8; ++x) a[x] = Zik[k][tm + x];
        #pragma unroll
        for (int y = 0; y < 8; ++y) b[y] = Zjk[k][tn + y];
        #pragma unroll
        for (int x = 0; x < 8; ++x)
            #pragma unroll
            for (int y = 0; y < 8; ++y)
                acc[x][y] = fmaf(a[x], b[y], acc[x][y]);
    }
    for (int x = 0; x < 8; ++x) {
        int gi = i0 + tm + x;
        if (gi >= n) break;
        long rowbase = (long)gi * n + j0 + tn;
        for (int y = 0; y < 8; y += 4) {
            int gj = j0 + tn + y;
            if (gj + 3 < n) {
                float4 o;
                o.x = sigf(acc[x][y + 0]);
                o.y = sigf(acc[x][y + 1]);
                o.z = sigf(acc[x][y + 2]);
                o.w = sigf(acc[x][y + 3]);
                *(float4*)(A + rowbase + y) = o;
            } else {
                for (int yy = y; yy < 8; ++yy) {
                    int g = j0 + tn + yy;
                    if (g < n) A[rowbase + yy] = sigf(acc[x][yy]);
                }
                break;
            }
        }
    }
}

extern "C" void kernel_launch(void* const* d_in, const int* in_sizes, int n_in,
                              void* d_out, int out_size, void* d_ws, size_t ws_size,
                              hipStream_t stream) {
    const float* feat     = (const float*)d_in[0];   // [20000,512]
    const int*   adj_rows = (const int*)d_in[1];     // [E]
    const int*   adj_cols = (const int*)d_in[2];     // [E]
    const float* adj_vals = (const float*)d_in[3];   // [E]
    const float* W1       = (const float*)d_in[4];   // [512,256]
    const float* W2       = (const float*)d_in[5];   // [256,64]

    float* out  = (float*)d_out;
    float* z    = out;                           // [20000,64]
    float* Arec = out + (long)NN * 64;           // [20000,20000]

    // workspace layout
    float* W12   = (float*)d_ws;                 // 512*64
    float* h     = W12 + 512 * 64;               // [20000,64] = feat @ W12
    float* hz    = h + (long)NN * 64;            // [20000,64] = A @ h
    float* val_s = hz + (long)NN * 64;           // [E]
    int*   col_s = (int*)(val_s + EE);           // [E]
    int*   cnt   = col_s + EE;                   // [N]
    int*   off   = cnt + NN;                     // [N+1]
    int*   cursor= off + NN + 1;                 // [N]

    // 1) CSR build (vals/rows/cols restored per call, so rebuild each call)
    fill_zero_i32<<<(NN + 255) / 256, 256, 0, stream>>>(cnt, NN);
    count_rows<<<(EE + 255) / 256, 256, 0, stream>>>(adj_rows, cnt, EE);
    scan_counts<<<1, 1024, 0, stream>>>(cnt, off, cursor, NN);
    scatter_edges<<<(EE + 255) / 256, 256, 0, stream>>>(adj_rows, adj_cols, adj_vals,
                                                        cursor, col_s, val_s, EE);

    // 2) W12 = W1 @ W2  [512,64];  h = feat @ W12  [20000,64]
    //    (A@(feat@W1))@W2 == A@(feat@(W1@W2)) by associativity/linearity
    sgemm64<<<dim3(1, (512 + 63) / 64), 256, 0, stream>>>(W1, W2, W12, 512, 256, 64);
    sgemm64<<<dim3(1, (NN + 63) / 64), 256, 0, stream>>>(feat, W12, h, NN, 512, 64);

    // 3) hz = A @ h ;  z = A @ hz
    spmm_csr64<<<(NN + 3) / 4, 256, 0, stream>>>(off, col_s, val_s, h, hz, NN);
    spmm_csr64<<<(NN + 3) / 4, 256, 0, stream>>>(off, col_s, val_s, hz, z, NN);

    // 4) A_rec = sigmoid(z @ z^T)
    decoder_zzT<<<dim3((NN + 127) / 128, (NN + 127) / 128), 256, 0, stream>>>(z, Arec, NN);
}

// Round 3
// 2363.733 us; speedup vs baseline: 1.2461x; 1.2461x over previous
//
#include <hip/hip_runtime.h>
#include <hip/hip_bf16.h>

#define NN 20000
#define EE 640000

// WS budget: harness ws_size is finite (~16 MB observed safe in R1).
// Total here = 3,932,769 floats = 15.73 MB. zT aliases h (dead after spmm#1).
// Exceeding ws_size corrupts neighboring allocations -> post-timing divergence.

__device__ __forceinline__ float sigf(float x) {
    return __builtin_amdgcn_rcpf(1.0f + __builtin_amdgcn_exp2f(x * -1.442695041f));
}

__global__ void fill_zero_i32(int* __restrict__ p, int n) {
    int i = blockIdx.x * 256 + threadIdx.x;
    if (i < n) p[i] = 0;
}

__global__ void count_rows(const int* __restrict__ rows, int* __restrict__ cnt, int e) {
    int i = blockIdx.x * 256 + threadIdx.x;
    if (i < e) atomicAdd(&cnt[rows[i]], 1);
}

__global__ __launch_bounds__(1024) void scan_counts(const int* __restrict__ cnt,
                                                    int* __restrict__ off,
                                                    int* __restrict__ cursor, int n) {
    __shared__ int part[1024];
    int tid = threadIdx.x;
    const int per = (n + 1023) / 1024;
    int base = tid * per;
    int s = 0;
    for (int i = 0; i < per; ++i) {
        int idx = base + i;
        if (idx < n) s += cnt[idx];
    }
    part[tid] = s;
    __syncthreads();
    for (int d = 1; d < 1024; d <<= 1) {
        int v = (tid >= d) ? part[tid - d] : 0;
        __syncthreads();
        part[tid] += v;
        __syncthreads();
    }
    int run = (tid == 0) ? 0 : part[tid - 1];
    for (int i = 0; i < per; ++i) {
        int idx = base + i;
        if (idx < n) {
            off[idx] = run;
            cursor[idx] = run;
            run += cnt[idx];
        }
    }
    if (tid == 1023) off[n] = part[1023];
}

__global__ void scatter_edges(const int* __restrict__ rows, const int* __restrict__ cols,
                              const float* __restrict__ vals, int* __restrict__ cursor,
                              int* __restrict__ col_s, float* __restrict__ val_s, int e) {
    int i = blockIdx.x * 256 + threadIdx.x;
    if (i < e) {
        int p = atomicAdd(&cursor[rows[i]], 1);
        col_s[p] = cols[i];
        val_s[p] = vals[i];
    }
}

// C[M,Nc] = A[M,K] @ B[K,Nc]; 64x64 tile, 256 threads, 4x4 per thread.
__global__ __launch_bounds__(256) void sgemm64(const float* __restrict__ A,
                                               const float* __restrict__ B,
                                               float* __restrict__ C, int M, int K, int Nc) {
    __shared__ float As[16][65];
    __shared__ float Bs[16][65];
    int tid = threadIdx.x;
    int tm = (tid >> 4) << 2;
    int tn = (tid & 15) << 2;
    int m0 = blockIdx.y * 64;
    int n0 = blockIdx.x * 64;
    float acc[4][4] = {};
    for (int k0 = 0; k0 < K; k0 += 16) {
        for (int i = tid; i < 64 * 16; i += 256) {
            int r = i >> 4, c = i & 15;
            int gr = m0 + r;
            As[c][r] = (gr < M) ? A[(long)gr * K + k0 + c] : 0.0f;
        }
        for (int i = tid; i < 16 * 64; i += 256) {
            int kk = i >> 6, c = i & 63;
            Bs[kk][c] = B[(long)(k0 + kk) * Nc + n0 + c];
        }
        __syncthreads();
        #pragma unroll
        for (int kk = 0; kk < 16; ++kk) {
            float a[4], b[4];
            #pragma unroll
            for (int x = 0; x < 4; ++x) a[x] = As[kk][tm + x];
            #pragma unroll
            for (int y = 0; y < 4; ++y) b[y] = Bs[kk][tn + y];
            #pragma unroll
            for (int x = 0; x < 4; ++x)
                #pragma unroll
                for (int y = 0; y < 4; ++y)
                    acc[x][y] = fmaf(a[x], b[y], acc[x][y]);
        }
        __syncthreads();
    }
    for (int x = 0; x < 4; ++x) {
        int gr = m0 + tm + x;
        if (gr < M) {
            #pragma unroll
            for (int y = 0; y < 4; ++y) C[(long)gr * Nc + n0 + tn + y] = acc[x][y];
        }
    }
}

// Y[row,:] = sum_e val[e] * X[col[e],:]; optionally also writes YT[64][n].
__global__ __launch_bounds__(256) void spmm_csr64(const int* __restrict__ off,
                                                  const int* __restrict__ col_s,
                                                  const float* __restrict__ val_s,
                                                  const float* __restrict__ X,
                                                  float* __restrict__ Y,
                                                  float* __restrict__ YT, int n) {
    int row = blockIdx.x * 4 + (threadIdx.x >> 6);
    if (row >= n) return;
    int lane = threadIdx.x & 63;
    int e0 = off[row], e1 = off[row + 1];
    float acc = 0.0f;
    for (int e = e0; e < e1; ++e) {
        acc = fmaf(val_s[e], X[(long)col_s[e] * 64 + lane], acc);
    }
    Y[(long)row * 64 + lane] = acc;
    if (YT) YT[(long)lane * n + row] = acc;
}

// A[i,j] = sigmoid(dot(Z[i],Z[j])). Reads pre-transposed ZT [64][n].
// 128x128 tile, 256 threads, 8x8/thread (j split into c0 and c0+64 chunks
// so every float4 store instruction is fully contiguous per 16-lane group).
// K staged in 2 chunks of 32 -> 32 KB LDS -> 4 blocks/CU.
__global__ __launch_bounds__(256, 4) void decoder_zzT(const float* __restrict__ ZT,
                                                      float* __restrict__ A, int n) {
    __shared__ float Zi[32][128];
    __shared__ float Zj[32][128];
    int tid = threadIdx.x;
    int i0 = blockIdx.y << 7;
    int j0 = blockIdx.x << 7;
    int tm = (tid >> 4) << 3;       // 8 rows per thread
    int c0 = (tid & 15) << 2;       // 4 cols, plus 4 more at c0+64
    int sc = (tid & 31) << 2;       // staging: float4 column
    int sk = tid >> 5;              // staging: k row (0..7)
    float acc[8][8] = {};
    for (int k0 = 0; k0 < 64; k0 += 32) {
        if (k0) __syncthreads();
        #pragma unroll
        for (int kq = 0; kq < 32; kq += 8) {
            int k = k0 + kq + sk;
            long rb = (long)k * n;
            float4 vi = make_float4(0.f, 0.f, 0.f, 0.f);
            float4 vj = make_float4(0.f, 0.f, 0.f, 0.f);
            if (i0 + sc + 4 <= n) vi = *(const float4*)(ZT + rb + i0 + sc);
            if (j0 + sc + 4 <= n) vj = *(const float4*)(ZT + rb + j0 + sc);
            *(float4*)&Zi[kq + sk][sc] = vi;
            *(float4*)&Zj[kq + sk][sc] = vj;
        }
        __syncthreads();
        #pragma unroll 8
        for (int k = 0; k < 32; ++k) {
            float a[8], b[8];
            *(float4*)&a[0] = *(const float4*)&Zi[k][tm];
            *(float4*)&a[4] = *(const float4*)&Zi[k][tm + 4];
            *(float4*)&b[0] = *(const float4*)&Zj[k][c0];
            *(float4*)&b[4] = *(const float4*)&Zj[k][c0 + 64];
            #pragma unroll
            for (int x = 0; x < 8; ++x)
                #pragma unroll
                for (int y = 0; y < 8; ++y)
                    acc[x][y] = fmaf(a[x], b[y], acc[x][y]);
        }
    }
    #pragma unroll
    for (int x = 0; x < 8; ++x) {
        int gi = i0 + tm + x;
        if (gi >= n) break;
        long rb = (long)gi * n;
        #pragma unroll
        for (int h = 0; h < 2; ++h) {
            int j = j0 + h * 64 + c0;
            if (j + 4 <= n) {
                float4 o;
                o.x = sigf(acc[x][h * 4 + 0]);
                o.y = sigf(acc[x][h * 4 + 1]);
                o.z = sigf(acc[x][h * 4 + 2]);
                o.w = sigf(acc[x][h * 4 + 3]);
                *(float4*)(A + rb + j) = o;
            } else {
                for (int q = 0; q < 4; ++q)
                    if (j + q < n) A[rb + j + q] = sigf(acc[x][h * 4 + q]);
            }
        }
    }
}

extern "C" void kernel_launch(void* const* d_in, const int* in_sizes, int n_in,
                              void* d_out, int out_size, void* d_ws, size_t ws_size,
                              hipStream_t stream) {
    const float* feat     = (const float*)d_in[0];
    const int*   adj_rows = (const int*)d_in[1];
    const int*   adj_cols = (const int*)d_in[2];
    const float* adj_vals = (const float*)d_in[3];
    const float* W1       = (const float*)d_in[4];
    const float* W2       = (const float*)d_in[5];

    float* out  = (float*)d_out;
    float* z    = out;                           // [20000,64]
    float* Arec = out + (long)NN * 64;           // [20000,20000]

    // Compact ws layout (15.73 MB total; zT aliases h which is dead after spmm#1)
    float* W12   = (float*)d_ws;                 // 512*64
    float* h     = W12 + 512 * 64;               // [N,64]  (also reused as zT [64,N])
    float* hz    = h + (long)NN * 64;            // [N,64]
    float* val_s = hz + (long)NN * 64;           // [E]
    int*   col_s = (int*)(val_s + EE);           // [E]
    int*   cnt   = col_s + EE;                   // [N]
    int*   off   = cnt + NN;                     // [N+1]
    int*   cursor= off + NN + 1;                 // [N]
    float* zT    = h;                            // alias: [64,N]

    fill_zero_i32<<<(NN + 255) / 256, 256, 0, stream>>>(cnt, NN);
    count_rows<<<(EE + 255) / 256, 256, 0, stream>>>(adj_rows, cnt, EE);
    scan_counts<<<1, 1024, 0, stream>>>(cnt, off, cursor, NN);
    scatter_edges<<<(EE + 255) / 256, 256, 0, stream>>>(adj_rows, adj_cols, adj_vals,
                                                        cursor, col_s, val_s, EE);

    // W12 = W1@W2 ; h = feat@W12  (associativity: (A(A(feat@W1)))@W2 == A(A(feat@(W1@W2))))
    sgemm64<<<dim3(1, (512 + 63) / 64), 256, 0, stream>>>(W1, W2, W12, 512, 256, 64);
    sgemm64<<<dim3(1, (NN + 63) / 64), 256, 0, stream>>>(feat, W12, h, NN, 512, 64);

    // hz = A@h ; then z = A@hz (also emits zT into h's storage — h is dead here)
    spmm_csr64<<<(NN + 3) / 4, 256, 0, stream>>>(off, col_s, val_s, h, hz, nullptr, NN);
    spmm_csr64<<<(NN + 3) / 4, 256, 0, stream>>>(off, col_s, val_s, hz, z, zT, NN);

    decoder_zzT<<<dim3((NN + 127) / 128, (NN + 127) / 128), 256, 0, stream>>>(zT, Arec, NN);
}